// Round 8
// baseline (322.496 us; speedup 1.0000x reference)
//
#include <hip/hip_runtime.h>
#include <hip/hip_bf16.h>
#include <math.h>

typedef __bf16 bf16;
typedef bf16 bf16x8 __attribute__((ext_vector_type(8)));
typedef float f32x4 __attribute__((ext_vector_type(4)));
typedef unsigned short ushort_t;
typedef unsigned long long u64;

#define N_NODES 100000
#define N_EDGES 640000
#define DD 128
#define MAXDEG 64
#define STAT_SCALE 1048576.0

__device__ __forceinline__ float gelu_fast(float x) {
    float z2 = x * (1.595769122f + 0.071354816f * x * x);
    return x * __builtin_amdgcn_rcpf(1.0f + __expf(-z2));
}

__device__ __forceinline__ ushort_t bf16_bits(float x) {
    bf16 h = (bf16)x;
    return __builtin_bit_cast(ushort_t, h);
}

__device__ __forceinline__ float bits_to_f(ushort_t u) {
    return __uint_as_float(((unsigned)u) << 16);
}

__device__ __forceinline__ long long to_fixed(double x) {
    return (long long)(x * STAT_SCALE + (x >= 0.0 ? 0.5 : -0.5));
}

__device__ __forceinline__ void stats_atomic(float lsum, float lsq, float* red,
                                             u64* dsum, u64* dsq) {
    int tid = threadIdx.x;
    red[tid] = lsum; __syncthreads();
    for (int s = 128; s > 0; s >>= 1) { if (tid < s) red[tid] += red[tid + s]; __syncthreads(); }
    float bs = red[0]; __syncthreads();
    red[tid] = lsq; __syncthreads();
    for (int s = 128; s > 0; s >>= 1) { if (tid < s) red[tid] += red[tid + s]; __syncthreads(); }
    if (tid == 0) {
        atomicAdd(dsum, (u64)to_fixed((double)bs));
        atomicAdd(dsq,  (u64)to_fixed((double)red[0]));
    }
}

__device__ __forceinline__ void stats_decode(const u64* stats, double cnt,
                                             float* mu, float* rs) {
    long long ss = (long long)stats[0], sq = (long long)stats[1];
    double mu_d = ((double)ss / STAT_SCALE) / cnt;
    double var  = ((double)sq / STAT_SCALE) / cnt - mu_d * mu_d;
    *mu = (float)mu_d;
    *rs = (float)(1.0 / sqrt(var + 1e-5));
}

#define PACK8(dstp, a, b) { \
    ushort_t o_[8] = {bf16_bits(a.x), bf16_bits(a.y), bf16_bits(a.z), bf16_bits(a.w), \
                      bf16_bits(b.x), bf16_bits(b.y), bf16_bits(b.z), bf16_bits(b.w)}; \
    *(uint4*)(dstp) = *(const uint4*)o_; }

// ---------------- K0: parallel init of cnt + stats ---------------------------
__global__ __launch_bounds__(256) void k0_init(int* __restrict__ cnt,
                                               u64* __restrict__ stats)
{
    int i = blockIdx.x * 256 + threadIdx.x;
    if (i < N_NODES) cnt[i] = 0;
    if (i < 4) stats[i] = 0ull;
}

// ---------------- K1: hpre = bf16(nf @ W1 + b1) + stats1 ---------------------
#define K1_TILES 1563
__global__ __launch_bounds__(256) void k1_gemm1(
    const float* __restrict__ nf, const float* __restrict__ W1,
    const float* __restrict__ b1, ushort_t* __restrict__ hpre,
    u64* __restrict__ stats, int nblocks)
{
    __shared__ bf16 Ash[64 * 136];
    __shared__ float red[256];
    const int tid = threadIdx.x;
    const int lane = tid & 63;
    const int w = tid >> 6;
    const int l15 = lane & 15, l4 = lane >> 4;

    bf16x8 bfrag[4][2];
    #pragma unroll
    for (int s = 0; s < 4; ++s)
        #pragma unroll
        for (int t = 0; t < 2; ++t) {
            int n = w * 32 + t * 16 + l15;
            #pragma unroll
            for (int j = 0; j < 8; ++j)
                bfrag[s][t][j] = (bf16)W1[(s * 32 + l4 * 8 + j) * DD + n];
        }
    float4 bias4[2];
    bias4[0] = *(const float4*)&b1[w * 32 + l4 * 4];
    bias4[1] = *(const float4*)&b1[w * 32 + 16 + l4 * 4];

    float lsum = 0.f, lsq = 0.f;
    const int srow = tid >> 2;
    const int q = tid & 3;

    float4 efr[8];
    {
        int grow = min(blockIdx.x * 64 + srow, N_NODES - 1);
        const float4* p = (const float4*)&nf[(size_t)grow * DD + q * 32];
        #pragma unroll
        for (int u = 0; u < 8; ++u) efr[u] = p[u];
    }

    for (int tile = blockIdx.x; tile < K1_TILES; tile += nblocks) {
        const int rbase = tile * 64;
        __syncthreads();
        #pragma unroll
        for (int u = 0; u < 4; ++u)
            PACK8(&Ash[srow * 136 + q * 32 + u * 8], efr[2 * u], efr[2 * u + 1]);
        __syncthreads();
        int nt = tile + nblocks;
        if (nt < K1_TILES) {
            int grow = min(nt * 64 + srow, N_NODES - 1);
            const float4* p = (const float4*)&nf[(size_t)grow * DD + q * 32];
            #pragma unroll
            for (int u = 0; u < 8; ++u) efr[u] = p[u];
        }
        f32x4 acc[4][2];
        #pragma unroll
        for (int r = 0; r < 4; ++r)
            #pragma unroll
            for (int t = 0; t < 2; ++t)
                acc[r][t] = (f32x4){0.f, 0.f, 0.f, 0.f};
        #pragma unroll
        for (int s = 0; s < 4; ++s)
            #pragma unroll
            for (int r = 0; r < 4; ++r) {
                bf16x8 a = *(const bf16x8*)&Ash[(r * 16 + l15) * 136 + s * 32 + l4 * 8];
                acc[r][0] = __builtin_amdgcn_mfma_f32_16x16x32_bf16(bfrag[s][0], a, acc[r][0], 0, 0, 0);
                acc[r][1] = __builtin_amdgcn_mfma_f32_16x16x32_bf16(bfrag[s][1], a, acc[r][1], 0, 0, 0);
            }
        #pragma unroll
        for (int r = 0; r < 4; ++r) {
            int row = rbase + r * 16 + l15;
            if (row < N_NODES) {
                #pragma unroll
                for (int t = 0; t < 2; ++t) {
                    int col = w * 32 + t * 16 + l4 * 4;
                    ushort_t o[4];
                    #pragma unroll
                    for (int j = 0; j < 4; ++j) {
                        float v = acc[r][t][j] + bias4[t][j];
                        lsum += v; lsq += v * v;
                        o[j] = bf16_bits(v);
                    }
                    *(uint2*)&hpre[(size_t)row * DD + col] = *(const uint2*)o;
                }
            }
        }
    }
    stats_atomic(lsum, lsq, red, &stats[0], &stats[1]);
}

// ---------------- K2b: hh = bf16( gelu(LN(hpre)) @ W2_bot + b2 ) -------------
// b2 folded in here so k4's epilogue is acc + hh[src] only.
__global__ __launch_bounds__(256) void k2b_gemmh(
    const ushort_t* __restrict__ hpre, const float* __restrict__ W2,
    const float* __restrict__ b2, const u64* __restrict__ stats,
    ushort_t* __restrict__ hh, int nblocks)
{
    __shared__ bf16 Ash[64 * 136];
    float mu, rs;
    stats_decode(stats, (double)N_NODES * DD, &mu, &rs);

    const int tid = threadIdx.x;
    const int lane = tid & 63;
    const int w = tid >> 6;
    const int l15 = lane & 15, l4 = lane >> 4;

    bf16x8 bfrag[4][2];
    #pragma unroll
    for (int s = 0; s < 4; ++s)
        #pragma unroll
        for (int t = 0; t < 2; ++t) {
            int n = w * 32 + t * 16 + l15;
            #pragma unroll
            for (int j = 0; j < 8; ++j)
                bfrag[s][t][j] = (bf16)W2[(DD + s * 32 + l4 * 8 + j) * DD + n];
        }
    float4 bias4[2];
    bias4[0] = *(const float4*)&b2[w * 32 + l4 * 4];
    bias4[1] = *(const float4*)&b2[w * 32 + 16 + l4 * 4];

    const int srow = tid >> 2;
    const int q = tid & 3;

    uint4 hr[4];
    {
        int grow = min(blockIdx.x * 64 + srow, N_NODES - 1);
        const uint4* p = (const uint4*)&hpre[(size_t)grow * DD + q * 32];
        #pragma unroll
        for (int u = 0; u < 4; ++u) hr[u] = p[u];
    }

    for (int tile = blockIdx.x; tile < K1_TILES; tile += nblocks) {
        const int rbase = tile * 64;
        __syncthreads();
        #pragma unroll
        for (int u = 0; u < 4; ++u) {
            const ushort_t* in = (const ushort_t*)&hr[u];
            ushort_t o[8];
            #pragma unroll
            for (int j = 0; j < 8; ++j)
                o[j] = bf16_bits(gelu_fast((bits_to_f(in[j]) - mu) * rs));
            *(uint4*)&Ash[srow * 136 + q * 32 + u * 8] = *(const uint4*)o;
        }
        __syncthreads();
        int nt = tile + nblocks;
        if (nt < K1_TILES) {
            int grow = min(nt * 64 + srow, N_NODES - 1);
            const uint4* p = (const uint4*)&hpre[(size_t)grow * DD + q * 32];
            #pragma unroll
            for (int u = 0; u < 4; ++u) hr[u] = p[u];
        }
        f32x4 acc[4][2];
        #pragma unroll
        for (int r = 0; r < 4; ++r)
            #pragma unroll
            for (int t = 0; t < 2; ++t)
                acc[r][t] = (f32x4){0.f, 0.f, 0.f, 0.f};
        #pragma unroll
        for (int s = 0; s < 4; ++s)
            #pragma unroll
            for (int r = 0; r < 4; ++r) {
                bf16x8 a = *(const bf16x8*)&Ash[(r * 16 + l15) * 136 + s * 32 + l4 * 8];
                acc[r][0] = __builtin_amdgcn_mfma_f32_16x16x32_bf16(bfrag[s][0], a, acc[r][0], 0, 0, 0);
                acc[r][1] = __builtin_amdgcn_mfma_f32_16x16x32_bf16(bfrag[s][1], a, acc[r][1], 0, 0, 0);
            }
        #pragma unroll
        for (int r = 0; r < 4; ++r) {
            int row = rbase + r * 16 + l15;
            if (row < N_NODES) {
                #pragma unroll
                for (int t = 0; t < 2; ++t) {
                    int col = w * 32 + t * 16 + l4 * 4;
                    ushort_t o[4];
                    #pragma unroll
                    for (int j = 0; j < 4; ++j)
                        o[j] = bf16_bits(acc[r][t][j] + bias4[t][j]);
                    *(uint2*)&hh[(size_t)row * DD + col] = *(const uint2*)o;
                }
            }
        }
    }
}

// ---------------- K4: e0 = bf16( ef @ W2_top + hh[src] ) + stats2 ------------
// Wave-owns-16-rows, B staged to LDS once per block, NO barriers in main loop.
#define K4_WTILES (N_EDGES / 16)
__global__ __launch_bounds__(256) void k4_gemm2(
    const float* __restrict__ ef, const ushort_t* __restrict__ hh,
    const int* __restrict__ eidx, const float* __restrict__ W2,
    ushort_t* __restrict__ e0, u64* __restrict__ stats, int nblocks)
{
    __shared__ bf16 Bsh[128 * 136];   // [n][k], 136-padded
    __shared__ float red[256];
    const int tid = threadIdx.x;
    const int lane = tid & 63;
    const int w = tid >> 6;
    const int l15 = lane & 15, l4 = lane >> 4;

    // stage W2_top transposed into LDS: Bsh[n*136 + k] = bf16(W2[k*128 + n])
    if (tid < 128) {
        int n = tid;
        #pragma unroll
        for (int kb = 0; kb < 16; ++kb) {
            float v[8];
            #pragma unroll
            for (int j = 0; j < 8; ++j)
                v[j] = W2[(size_t)(kb * 8 + j) * DD + n];   // coalesced across tid
            ushort_t o[8];
            #pragma unroll
            for (int j = 0; j < 8; ++j) o[j] = bf16_bits(v[j]);
            *(uint4*)&Bsh[n * 136 + kb * 8] = *(const uint4*)o;
        }
    }
    __syncthreads();

    float lsum = 0.f, lsq = 0.f;

    for (int g = blockIdx.x * 4 + w; g < K4_WTILES; g += nblocks * 4) {
        const int row = g * 16 + l15;
        // gather prefetch (dependent chain issued first)
        int src = eidx[(size_t)row * 2];
        // A panel: 16 rows x 128 cols fp32, this lane: rows=l15, k-chunk=l4*8
        float4 a0[4], a1[4];
        #pragma unroll
        for (int s = 0; s < 4; ++s) {
            const float4* pa = (const float4*)&ef[(size_t)row * DD + s * 32 + l4 * 8];
            a0[s] = pa[0]; a1[s] = pa[1];
        }
        uint2 hv[8];
        #pragma unroll
        for (int t = 0; t < 8; ++t)
            hv[t] = *(const uint2*)&hh[(size_t)src * DD + t * 16 + l4 * 4];

        f32x4 acc[8];
        #pragma unroll
        for (int t = 0; t < 8; ++t) acc[t] = (f32x4){0.f, 0.f, 0.f, 0.f};

        #pragma unroll
        for (int s = 0; s < 4; ++s) {
            ushort_t af[8] = {bf16_bits(a0[s].x), bf16_bits(a0[s].y), bf16_bits(a0[s].z), bf16_bits(a0[s].w),
                              bf16_bits(a1[s].x), bf16_bits(a1[s].y), bf16_bits(a1[s].z), bf16_bits(a1[s].w)};
            bf16x8 afrag = *(const bf16x8*)af;
            #pragma unroll
            for (int t = 0; t < 8; ++t) {
                bf16x8 bfrag = *(const bf16x8*)&Bsh[(t * 16 + l15) * 136 + s * 32 + l4 * 8];
                acc[t] = __builtin_amdgcn_mfma_f32_16x16x32_bf16(bfrag, afrag, acc[t], 0, 0, 0);
            }
        }

        #pragma unroll
        for (int t = 0; t < 8; ++t) {
            float hadd[4] = {bits_to_f((ushort_t)(hv[t].x & 0xffff)),
                             bits_to_f((ushort_t)(hv[t].x >> 16)),
                             bits_to_f((ushort_t)(hv[t].y & 0xffff)),
                             bits_to_f((ushort_t)(hv[t].y >> 16))};
            ushort_t o[4];
            #pragma unroll
            for (int j = 0; j < 4; ++j) {
                float v = acc[t][j] + hadd[j];
                lsum += v; lsq += v * v;
                o[j] = bf16_bits(v);
            }
            *(uint2*)&e0[(size_t)row * DD + t * 16 + l4 * 4] = *(const uint2*)o;
        }
    }
    stats_atomic(lsum, lsq, red, &stats[2], &stats[3]);
}

// ---------------- K7: bucket edges by dst ------------------------------------
__global__ __launch_bounds__(256) void k7_fill(
    const int* __restrict__ eidx, int* __restrict__ cnt, int* __restrict__ slot)
{
    int e = blockIdx.x * 256 + threadIdx.x;
    if (e >= N_EDGES) return;
    int dst = eidx[(size_t)e * 2 + 1];
    int pos = atomicAdd(&cnt[dst], 1);
    if (pos < MAXDEG) slot[dst * MAXDEG + pos] = e;
}

// ---------------- K8: per-node gather + norm + fast-gelu + mean --------------
__global__ __launch_bounds__(256) void k8_gather(
    const ushort_t* __restrict__ e0v, const int* __restrict__ slot,
    const int* __restrict__ cnt, const u64* __restrict__ stats,
    float* __restrict__ out)
{
    float mu, rs;
    stats_decode(stats + 2, (double)N_EDGES * DD, &mu, &rs);
    int node = (int)((blockIdx.x * 256 + threadIdx.x) >> 6);
    int lane = threadIdx.x & 63;
    if (node >= N_NODES) return;
    const int hl = lane >> 5;
    const int l31 = lane & 31;
    int c = cnt[node];
    int m = min(c, MAXDEG);
    int myslot = (lane < m) ? slot[node * MAXDEG + lane] : 0;
    float a0 = 0.f, a1 = 0.f, a2 = 0.f, a3 = 0.f;
    const size_t off = (size_t)(l31 * 4);

    int steps = m >> 1;
    int s = 0;
    for (; s + 2 <= steps; s += 2) {
        int eA = __shfl(myslot, 2 * s + hl);
        int eB = __shfl(myslot, 2 * (s + 1) + hl);
        uint2 uA = *(const uint2*)&e0v[(size_t)eA * DD + off];
        uint2 uB = *(const uint2*)&e0v[(size_t)eB * DD + off];
        a0 += gelu_fast((__uint_as_float(uA.x << 16) - mu) * rs);
        a1 += gelu_fast((__uint_as_float(uA.x & 0xffff0000u) - mu) * rs);
        a2 += gelu_fast((__uint_as_float(uA.y << 16) - mu) * rs);
        a3 += gelu_fast((__uint_as_float(uA.y & 0xffff0000u) - mu) * rs);
        a0 += gelu_fast((__uint_as_float(uB.x << 16) - mu) * rs);
        a1 += gelu_fast((__uint_as_float(uB.x & 0xffff0000u) - mu) * rs);
        a2 += gelu_fast((__uint_as_float(uB.y << 16) - mu) * rs);
        a3 += gelu_fast((__uint_as_float(uB.y & 0xffff0000u) - mu) * rs);
    }
    for (; s < steps; ++s) {
        int eA = __shfl(myslot, 2 * s + hl);
        uint2 uA = *(const uint2*)&e0v[(size_t)eA * DD + off];
        a0 += gelu_fast((__uint_as_float(uA.x << 16) - mu) * rs);
        a1 += gelu_fast((__uint_as_float(uA.x & 0xffff0000u) - mu) * rs);
        a2 += gelu_fast((__uint_as_float(uA.y << 16) - mu) * rs);
        a3 += gelu_fast((__uint_as_float(uA.y & 0xffff0000u) - mu) * rs);
    }
    if (m & 1) {
        int eA = __shfl(myslot, m - 1);
        uint2 uA = *(const uint2*)&e0v[(size_t)eA * DD + off];
        float g0 = gelu_fast((__uint_as_float(uA.x << 16) - mu) * rs);
        float g1 = gelu_fast((__uint_as_float(uA.x & 0xffff0000u) - mu) * rs);
        float g2 = gelu_fast((__uint_as_float(uA.y << 16) - mu) * rs);
        float g3 = gelu_fast((__uint_as_float(uA.y & 0xffff0000u) - mu) * rs);
        if (hl == 0) { a0 += g0; a1 += g1; a2 += g2; a3 += g3; }
    }
    a0 += __shfl_xor(a0, 32);
    a1 += __shfl_xor(a1, 32);
    a2 += __shfl_xor(a2, 32);
    a3 += __shfl_xor(a3, 32);
    if (hl == 0) {
        float inv = c > 0 ? 1.0f / (float)c : 0.f;
        float4 res = {a0 * inv, a1 * inv, a2 * inv, a3 * inv};
        *(float4*)&out[(size_t)node * DD + l31 * 4] = res;
    }
}

// ---------------- launch -----------------------------------------------------
extern "C" void kernel_launch(void* const* d_in, const int* in_sizes, int n_in,
                              void* d_out, int out_size, void* d_ws, size_t ws_size,
                              hipStream_t stream) {
    const float* ef  = (const float*)d_in[0];
    const float* nf  = (const float*)d_in[1];
    const int*   eix = (const int*)d_in[2];
    const float* W1  = (const float*)d_in[3];
    const float* b1  = (const float*)d_in[4];
    const float* W2  = (const float*)d_in[5];
    const float* b2  = (const float*)d_in[6];
    float* out = (float*)d_out;
    char* ws = (char*)d_ws;

    ushort_t* hpre  = (ushort_t*)(ws + 0);           // 25,600,000
    ushort_t* hh    = (ushort_t*)(ws + 25600000);    // 25,600,000
    ushort_t* e0    = (ushort_t*)(ws + 51200000);    // 163,840,000
    int*      cnt   = (int*)(ws + 215040000);        // 400,000
    u64*      stats = (u64*)(ws + 215440000);        // 64 B
    int*      slot  = (int*)(ws + 215440064);        // 25,600,000

    k0_init<<<391, 256, 0, stream>>>(cnt, stats);
    k7_fill<<<2500, 256, 0, stream>>>(eix, cnt, slot);
    k1_gemm1<<<782, 256, 0, stream>>>(nf, W1, b1, hpre, stats, 782);
    k2b_gemmh<<<782, 256, 0, stream>>>(hpre, W2, b2, stats, hh, 782);
    k4_gemm2<<<2500, 256, 0, stream>>>(ef, hh, eix, W2, e0, stats, 2500);
    k8_gather<<<25000, 256, 0, stream>>>(e0, slot, cnt, stats, out);
}

// Round 9
// 301.426 us; speedup vs baseline: 1.0699x; 1.0699x over previous
//
#include <hip/hip_runtime.h>
#include <hip/hip_bf16.h>
#include <math.h>

typedef __bf16 bf16;
typedef bf16 bf16x8 __attribute__((ext_vector_type(8)));
typedef float f32x4 __attribute__((ext_vector_type(4)));
typedef unsigned short ushort_t;
typedef unsigned long long u64;

#define N_NODES 100000
#define N_EDGES 640000
#define DD 128
#define MAXDEG 64
#define STAT_SCALE 1048576.0

__device__ __forceinline__ float gelu_fast(float x) {
    float z2 = x * (1.595769122f + 0.071354816f * x * x);
    return x * __builtin_amdgcn_rcpf(1.0f + __expf(-z2));
}

__device__ __forceinline__ ushort_t bf16_bits(float x) {
    bf16 h = (bf16)x;
    return __builtin_bit_cast(ushort_t, h);
}

__device__ __forceinline__ float bits_to_f(ushort_t u) {
    return __uint_as_float(((unsigned)u) << 16);
}

__device__ __forceinline__ long long to_fixed(double x) {
    return (long long)(x * STAT_SCALE + (x >= 0.0 ? 0.5 : -0.5));
}

__device__ __forceinline__ void stats_atomic(float lsum, float lsq, float* red,
                                             u64* dsum, u64* dsq) {
    int tid = threadIdx.x;
    red[tid] = lsum; __syncthreads();
    for (int s = 128; s > 0; s >>= 1) { if (tid < s) red[tid] += red[tid + s]; __syncthreads(); }
    float bs = red[0]; __syncthreads();
    red[tid] = lsq; __syncthreads();
    for (int s = 128; s > 0; s >>= 1) { if (tid < s) red[tid] += red[tid + s]; __syncthreads(); }
    if (tid == 0) {
        atomicAdd(dsum, (u64)to_fixed((double)bs));
        atomicAdd(dsq,  (u64)to_fixed((double)red[0]));
    }
}

__device__ __forceinline__ void stats_decode(const u64* stats, double cnt,
                                             float* mu, float* rs) {
    long long ss = (long long)stats[0], sq = (long long)stats[1];
    double mu_d = ((double)ss / STAT_SCALE) / cnt;
    double var  = ((double)sq / STAT_SCALE) / cnt - mu_d * mu_d;
    *mu = (float)mu_d;
    *rs = (float)(1.0 / sqrt(var + 1e-5));
}

#define PACK8(dstp, a, b) { \
    ushort_t o_[8] = {bf16_bits(a.x), bf16_bits(a.y), bf16_bits(a.z), bf16_bits(a.w), \
                      bf16_bits(b.x), bf16_bits(b.y), bf16_bits(b.z), bf16_bits(b.w)}; \
    *(uint4*)(dstp) = *(const uint4*)o_; }

// ---------------- K0: parallel init of cnt + stats ---------------------------
__global__ __launch_bounds__(256) void k0_init(int* __restrict__ cnt,
                                               u64* __restrict__ stats)
{
    int i = blockIdx.x * 256 + threadIdx.x;
    if (i < N_NODES) cnt[i] = 0;
    if (i < 4) stats[i] = 0ull;
}

// ---------------- K1: hpre = bf16(nf @ W1 + b1) + stats1 ---------------------
// Double-buffered LDS, ONE barrier per 64-row tile; A(t+1) prefetched in regs
// during MFMA(t) and consumed at the next LDS-write (no barrier in between).
#define K1_TILES 1563
__global__ __launch_bounds__(256) void k1_gemm1(
    const float* __restrict__ nf, const float* __restrict__ W1,
    const float* __restrict__ b1, ushort_t* __restrict__ hpre,
    u64* __restrict__ stats, int nblocks)
{
    __shared__ bf16 Ash[2][64 * 136];
    __shared__ float red[256];
    const int tid = threadIdx.x;
    const int lane = tid & 63;
    const int w = tid >> 6;
    const int l15 = lane & 15, l4 = lane >> 4;

    bf16x8 bfrag[4][2];
    #pragma unroll
    for (int s = 0; s < 4; ++s)
        #pragma unroll
        for (int t = 0; t < 2; ++t) {
            int n = w * 32 + t * 16 + l15;
            #pragma unroll
            for (int j = 0; j < 8; ++j)
                bfrag[s][t][j] = (bf16)W1[(s * 32 + l4 * 8 + j) * DD + n];
        }
    float4 bias4[2];
    bias4[0] = *(const float4*)&b1[w * 32 + l4 * 4];
    bias4[1] = *(const float4*)&b1[w * 32 + 16 + l4 * 4];

    float lsum = 0.f, lsq = 0.f;
    const int srow = tid >> 2;
    const int q = tid & 3;

    float4 efr[8];
    {
        int grow = min(blockIdx.x * 64 + srow, N_NODES - 1);
        const float4* p = (const float4*)&nf[(size_t)grow * DD + q * 32];
        #pragma unroll
        for (int u = 0; u < 8; ++u) efr[u] = p[u];
    }

    int buf = 0;
    for (int tile = blockIdx.x; tile < K1_TILES; tile += nblocks) {
        const int rbase = tile * 64;
        #pragma unroll
        for (int u = 0; u < 4; ++u)
            PACK8(&Ash[buf][srow * 136 + q * 32 + u * 8], efr[2 * u], efr[2 * u + 1]);
        __syncthreads();
        int nt = tile + nblocks;
        if (nt < K1_TILES) {
            int grow = min(nt * 64 + srow, N_NODES - 1);
            const float4* p = (const float4*)&nf[(size_t)grow * DD + q * 32];
            #pragma unroll
            for (int u = 0; u < 8; ++u) efr[u] = p[u];
        }
        f32x4 acc[4][2];
        #pragma unroll
        for (int r = 0; r < 4; ++r)
            #pragma unroll
            for (int t = 0; t < 2; ++t)
                acc[r][t] = (f32x4){0.f, 0.f, 0.f, 0.f};
        #pragma unroll
        for (int s = 0; s < 4; ++s)
            #pragma unroll
            for (int r = 0; r < 4; ++r) {
                bf16x8 a = *(const bf16x8*)&Ash[buf][(r * 16 + l15) * 136 + s * 32 + l4 * 8];
                acc[r][0] = __builtin_amdgcn_mfma_f32_16x16x32_bf16(bfrag[s][0], a, acc[r][0], 0, 0, 0);
                acc[r][1] = __builtin_amdgcn_mfma_f32_16x16x32_bf16(bfrag[s][1], a, acc[r][1], 0, 0, 0);
            }
        #pragma unroll
        for (int r = 0; r < 4; ++r) {
            int row = rbase + r * 16 + l15;
            if (row < N_NODES) {
                #pragma unroll
                for (int t = 0; t < 2; ++t) {
                    int col = w * 32 + t * 16 + l4 * 4;
                    ushort_t o[4];
                    #pragma unroll
                    for (int j = 0; j < 4; ++j) {
                        float v = acc[r][t][j] + bias4[t][j];
                        lsum += v; lsq += v * v;
                        o[j] = bf16_bits(v);
                    }
                    *(uint2*)&hpre[(size_t)row * DD + col] = *(const uint2*)o;
                }
            }
        }
        buf ^= 1;
    }
    stats_atomic(lsum, lsq, red, &stats[0], &stats[1]);
}

// ---------------- K2b: hh = bf16( gelu(LN(hpre)) @ W2_bot + b2 ) -------------
__global__ __launch_bounds__(256) void k2b_gemmh(
    const ushort_t* __restrict__ hpre, const float* __restrict__ W2,
    const float* __restrict__ b2, const u64* __restrict__ stats,
    ushort_t* __restrict__ hh, int nblocks)
{
    __shared__ bf16 Ash[2][64 * 136];
    float mu, rs;
    stats_decode(stats, (double)N_NODES * DD, &mu, &rs);

    const int tid = threadIdx.x;
    const int lane = tid & 63;
    const int w = tid >> 6;
    const int l15 = lane & 15, l4 = lane >> 4;

    bf16x8 bfrag[4][2];
    #pragma unroll
    for (int s = 0; s < 4; ++s)
        #pragma unroll
        for (int t = 0; t < 2; ++t) {
            int n = w * 32 + t * 16 + l15;
            #pragma unroll
            for (int j = 0; j < 8; ++j)
                bfrag[s][t][j] = (bf16)W2[(DD + s * 32 + l4 * 8 + j) * DD + n];
        }
    float4 bias4[2];
    bias4[0] = *(const float4*)&b2[w * 32 + l4 * 4];
    bias4[1] = *(const float4*)&b2[w * 32 + 16 + l4 * 4];

    const int srow = tid >> 2;
    const int q = tid & 3;

    uint4 hr[4];
    {
        int grow = min(blockIdx.x * 64 + srow, N_NODES - 1);
        const uint4* p = (const uint4*)&hpre[(size_t)grow * DD + q * 32];
        #pragma unroll
        for (int u = 0; u < 4; ++u) hr[u] = p[u];
    }

    int buf = 0;
    for (int tile = blockIdx.x; tile < K1_TILES; tile += nblocks) {
        const int rbase = tile * 64;
        #pragma unroll
        for (int u = 0; u < 4; ++u) {
            const ushort_t* in = (const ushort_t*)&hr[u];
            ushort_t o[8];
            #pragma unroll
            for (int j = 0; j < 8; ++j)
                o[j] = bf16_bits(gelu_fast((bits_to_f(in[j]) - mu) * rs));
            *(uint4*)&Ash[buf][srow * 136 + q * 32 + u * 8] = *(const uint4*)o;
        }
        __syncthreads();
        int nt = tile + nblocks;
        if (nt < K1_TILES) {
            int grow = min(nt * 64 + srow, N_NODES - 1);
            const uint4* p = (const uint4*)&hpre[(size_t)grow * DD + q * 32];
            #pragma unroll
            for (int u = 0; u < 4; ++u) hr[u] = p[u];
        }
        f32x4 acc[4][2];
        #pragma unroll
        for (int r = 0; r < 4; ++r)
            #pragma unroll
            for (int t = 0; t < 2; ++t)
                acc[r][t] = (f32x4){0.f, 0.f, 0.f, 0.f};
        #pragma unroll
        for (int s = 0; s < 4; ++s)
            #pragma unroll
            for (int r = 0; r < 4; ++r) {
                bf16x8 a = *(const bf16x8*)&Ash[buf][(r * 16 + l15) * 136 + s * 32 + l4 * 8];
                acc[r][0] = __builtin_amdgcn_mfma_f32_16x16x32_bf16(bfrag[s][0], a, acc[r][0], 0, 0, 0);
                acc[r][1] = __builtin_amdgcn_mfma_f32_16x16x32_bf16(bfrag[s][1], a, acc[r][1], 0, 0, 0);
            }
        #pragma unroll
        for (int r = 0; r < 4; ++r) {
            int row = rbase + r * 16 + l15;
            if (row < N_NODES) {
                #pragma unroll
                for (int t = 0; t < 2; ++t) {
                    int col = w * 32 + t * 16 + l4 * 4;
                    ushort_t o[4];
                    #pragma unroll
                    for (int j = 0; j < 4; ++j)
                        o[j] = bf16_bits(acc[r][t][j] + bias4[t][j]);
                    *(uint2*)&hh[(size_t)row * DD + col] = *(const uint2*)o;
                }
            }
        }
        buf ^= 1;
    }
}

// ---------------- K4: e0 = bf16( ef @ W2_top + hh[src] ) + stats2 ------------
// dbuf LDS, ONE barrier/tile; A(t+1)+srcv(t+1) prefetched during MFMA(t);
// hv(t) issued at barrier-exit (srcv resident), consumed in epilogue.
#define K4_TILES (N_EDGES / 64)
__global__ __launch_bounds__(256) void k4_gemm2(
    const float* __restrict__ ef, const ushort_t* __restrict__ hh,
    const int* __restrict__ eidx, const float* __restrict__ W2,
    ushort_t* __restrict__ e0, u64* __restrict__ stats, int nblocks)
{
    __shared__ bf16 Ash[2][64 * 136];
    __shared__ float red[256];
    const int tid = threadIdx.x;
    const int lane = tid & 63;
    const int w = tid >> 6;
    const int l15 = lane & 15, l4 = lane >> 4;

    bf16x8 bfrag[4][2];
    #pragma unroll
    for (int s = 0; s < 4; ++s)
        #pragma unroll
        for (int t = 0; t < 2; ++t) {
            int n = w * 32 + t * 16 + l15;
            #pragma unroll
            for (int j = 0; j < 8; ++j)
                bfrag[s][t][j] = (bf16)W2[(s * 32 + l4 * 8 + j) * DD + n];
        }

    float lsum = 0.f, lsq = 0.f;
    const int srow = tid >> 2;
    const int q = tid & 3;

    float4 efr[8];
    int srcv[4];
    {
        const float4* p = (const float4*)&ef[(size_t)(blockIdx.x * 64 + srow) * DD + q * 32];
        #pragma unroll
        for (int u = 0; u < 8; ++u) efr[u] = p[u];
        #pragma unroll
        for (int r = 0; r < 4; ++r)
            srcv[r] = eidx[(size_t)(blockIdx.x * 64 + r * 16 + l15) * 2];
    }

    int buf = 0;
    for (int tile = blockIdx.x; tile < K4_TILES; tile += nblocks) {
        const int ebase = tile * 64;
        #pragma unroll
        for (int u = 0; u < 4; ++u)
            PACK8(&Ash[buf][srow * 136 + q * 32 + u * 8], efr[2 * u], efr[2 * u + 1]);
        __syncthreads();
        // current-tile gather: srcv loaded one tile ago, drained by barrier
        uint2 hv[4][2];
        #pragma unroll
        for (int r = 0; r < 4; ++r)
            #pragma unroll
            for (int t = 0; t < 2; ++t)
                hv[r][t] = *(const uint2*)&hh[(size_t)srcv[r] * DD + w * 32 + t * 16 + l4 * 4];
        // next-tile prefetches (consumed after MFMA / next LDS-write)
        const int nt = tile + nblocks;
        if (nt < K4_TILES) {
            const float4* p = (const float4*)&ef[(size_t)(nt * 64 + srow) * DD + q * 32];
            #pragma unroll
            for (int u = 0; u < 8; ++u) efr[u] = p[u];
            #pragma unroll
            for (int r = 0; r < 4; ++r)
                srcv[r] = eidx[(size_t)(nt * 64 + r * 16 + l15) * 2];
        }
        f32x4 acc[4][2];
        #pragma unroll
        for (int r = 0; r < 4; ++r)
            #pragma unroll
            for (int t = 0; t < 2; ++t)
                acc[r][t] = (f32x4){0.f, 0.f, 0.f, 0.f};
        #pragma unroll
        for (int s = 0; s < 4; ++s)
            #pragma unroll
            for (int r = 0; r < 4; ++r) {
                bf16x8 a = *(const bf16x8*)&Ash[buf][(r * 16 + l15) * 136 + s * 32 + l4 * 8];
                acc[r][0] = __builtin_amdgcn_mfma_f32_16x16x32_bf16(bfrag[s][0], a, acc[r][0], 0, 0, 0);
                acc[r][1] = __builtin_amdgcn_mfma_f32_16x16x32_bf16(bfrag[s][1], a, acc[r][1], 0, 0, 0);
            }
        #pragma unroll
        for (int r = 0; r < 4; ++r) {
            int row = ebase + r * 16 + l15;
            #pragma unroll
            for (int t = 0; t < 2; ++t) {
                int col = w * 32 + t * 16 + l4 * 4;
                float hadd[4] = {bits_to_f((ushort_t)(hv[r][t].x & 0xffff)),
                                 bits_to_f((ushort_t)(hv[r][t].x >> 16)),
                                 bits_to_f((ushort_t)(hv[r][t].y & 0xffff)),
                                 bits_to_f((ushort_t)(hv[r][t].y >> 16))};
                ushort_t o[4];
                #pragma unroll
                for (int j = 0; j < 4; ++j) {
                    float v = acc[r][t][j] + hadd[j];
                    lsum += v; lsq += v * v;
                    o[j] = bf16_bits(v);
                }
                *(uint2*)&e0[(size_t)row * DD + col] = *(const uint2*)o;
            }
        }
        buf ^= 1;
    }
    stats_atomic(lsum, lsq, red, &stats[2], &stats[3]);
}

// ---------------- K7: bucket edges by dst ------------------------------------
__global__ __launch_bounds__(256) void k7_fill(
    const int* __restrict__ eidx, int* __restrict__ cnt, int* __restrict__ slot)
{
    int e = blockIdx.x * 256 + threadIdx.x;
    if (e >= N_EDGES) return;
    int dst = eidx[(size_t)e * 2 + 1];
    int pos = atomicAdd(&cnt[dst], 1);
    if (pos < MAXDEG) slot[dst * MAXDEG + pos] = e;
}

// ---------------- K8: per-node gather + norm + fast-gelu + mean --------------
__global__ __launch_bounds__(256) void k8_gather(
    const ushort_t* __restrict__ e0v, const int* __restrict__ slot,
    const int* __restrict__ cnt, const u64* __restrict__ stats,
    float* __restrict__ out)
{
    float mu, rs;
    stats_decode(stats + 2, (double)N_EDGES * DD, &mu, &rs);
    int node = (int)((blockIdx.x * 256 + threadIdx.x) >> 6);
    int lane = threadIdx.x & 63;
    if (node >= N_NODES) return;
    const int hl = lane >> 5;
    const int l31 = lane & 31;
    int c = cnt[node];
    int m = min(c, MAXDEG);
    int myslot = (lane < m) ? slot[node * MAXDEG + lane] : 0;
    float a0 = 0.f, a1 = 0.f, a2 = 0.f, a3 = 0.f;
    const size_t off = (size_t)(l31 * 4);

    int steps = m >> 1;
    int s = 0;
    for (; s + 2 <= steps; s += 2) {
        int eA = __shfl(myslot, 2 * s + hl);
        int eB = __shfl(myslot, 2 * (s + 1) + hl);
        uint2 uA = *(const uint2*)&e0v[(size_t)eA * DD + off];
        uint2 uB = *(const uint2*)&e0v[(size_t)eB * DD + off];
        a0 += gelu_fast((__uint_as_float(uA.x << 16) - mu) * rs);
        a1 += gelu_fast((__uint_as_float(uA.x & 0xffff0000u) - mu) * rs);
        a2 += gelu_fast((__uint_as_float(uA.y << 16) - mu) * rs);
        a3 += gelu_fast((__uint_as_float(uA.y & 0xffff0000u) - mu) * rs);
        a0 += gelu_fast((__uint_as_float(uB.x << 16) - mu) * rs);
        a1 += gelu_fast((__uint_as_float(uB.x & 0xffff0000u) - mu) * rs);
        a2 += gelu_fast((__uint_as_float(uB.y << 16) - mu) * rs);
        a3 += gelu_fast((__uint_as_float(uB.y & 0xffff0000u) - mu) * rs);
    }
    for (; s < steps; ++s) {
        int eA = __shfl(myslot, 2 * s + hl);
        uint2 uA = *(const uint2*)&e0v[(size_t)eA * DD + off];
        a0 += gelu_fast((__uint_as_float(uA.x << 16) - mu) * rs);
        a1 += gelu_fast((__uint_as_float(uA.x & 0xffff0000u) - mu) * rs);
        a2 += gelu_fast((__uint_as_float(uA.y << 16) - mu) * rs);
        a3 += gelu_fast((__uint_as_float(uA.y & 0xffff0000u) - mu) * rs);
    }
    if (m & 1) {
        int eA = __shfl(myslot, m - 1);
        uint2 uA = *(const uint2*)&e0v[(size_t)eA * DD + off];
        float g0 = gelu_fast((__uint_as_float(uA.x << 16) - mu) * rs);
        float g1 = gelu_fast((__uint_as_float(uA.x & 0xffff0000u) - mu) * rs);
        float g2 = gelu_fast((__uint_as_float(uA.y << 16) - mu) * rs);
        float g3 = gelu_fast((__uint_as_float(uA.y & 0xffff0000u) - mu) * rs);
        if (hl == 0) { a0 += g0; a1 += g1; a2 += g2; a3 += g3; }
    }
    a0 += __shfl_xor(a0, 32);
    a1 += __shfl_xor(a1, 32);
    a2 += __shfl_xor(a2, 32);
    a3 += __shfl_xor(a3, 32);
    if (hl == 0) {
        float inv = c > 0 ? 1.0f / (float)c : 0.f;
        float4 res = {a0 * inv, a1 * inv, a2 * inv, a3 * inv};
        *(float4*)&out[(size_t)node * DD + l31 * 4] = res;
    }
}

// ---------------- launch -----------------------------------------------------
extern "C" void kernel_launch(void* const* d_in, const int* in_sizes, int n_in,
                              void* d_out, int out_size, void* d_ws, size_t ws_size,
                              hipStream_t stream) {
    const float* ef  = (const float*)d_in[0];
    const float* nf  = (const float*)d_in[1];
    const int*   eix = (const int*)d_in[2];
    const float* W1  = (const float*)d_in[3];
    const float* b1  = (const float*)d_in[4];
    const float* W2  = (const float*)d_in[5];
    const float* b2  = (const float*)d_in[6];
    float* out = (float*)d_out;
    char* ws = (char*)d_ws;

    ushort_t* hpre  = (ushort_t*)(ws + 0);           // 25,600,000
    ushort_t* hh    = (ushort_t*)(ws + 25600000);    // 25,600,000
    ushort_t* e0    = (ushort_t*)(ws + 51200000);    // 163,840,000
    int*      cnt   = (int*)(ws + 215040000);        // 400,000
    u64*      stats = (u64*)(ws + 215440000);        // 64 B
    int*      slot  = (int*)(ws + 215440064);        // 25,600,000

    k0_init<<<391, 256, 0, stream>>>(cnt, stats);
    k7_fill<<<2500, 256, 0, stream>>>(eix, cnt, slot);
    k1_gemm1<<<782, 256, 0, stream>>>(nf, W1, b1, hpre, stats, 782);
    k2b_gemmh<<<782, 256, 0, stream>>>(hpre, W2, b2, stats, hh, 782);
    k4_gemm2<<<2500, 256, 0, stream>>>(ef, hh, eix, W2, e0, stats, 2500);
    k8_gather<<<25000, 256, 0, stream>>>(e0, slot, cnt, stats, out);
}

// Round 10
// 298.695 us; speedup vs baseline: 1.0797x; 1.0091x over previous
//
#include <hip/hip_runtime.h>
#include <hip/hip_bf16.h>
#include <math.h>

typedef __bf16 bf16;
typedef bf16 bf16x8 __attribute__((ext_vector_type(8)));
typedef float f32x4 __attribute__((ext_vector_type(4)));
typedef unsigned short ushort_t;
typedef unsigned long long u64;

#define N_NODES 100000
#define N_EDGES 640000
#define DD 128
#define MAXDEG 64
#define STAT_SCALE 1048576.0

__device__ __forceinline__ float gelu_fast(float x) {
    float z2 = x * (1.595769122f + 0.071354816f * x * x);
    return x * __builtin_amdgcn_rcpf(1.0f + __expf(-z2));
}

__device__ __forceinline__ ushort_t bf16_bits(float x) {
    bf16 h = (bf16)x;
    return __builtin_bit_cast(ushort_t, h);
}

__device__ __forceinline__ float bits_to_f(ushort_t u) {
    return __uint_as_float(((unsigned)u) << 16);
}

__device__ __forceinline__ long long to_fixed(double x) {
    return (long long)(x * STAT_SCALE + (x >= 0.0 ? 0.5 : -0.5));
}

__device__ __forceinline__ void stats_atomic(float lsum, float lsq, float* red,
                                             u64* dsum, u64* dsq) {
    int tid = threadIdx.x;
    red[tid] = lsum; __syncthreads();
    for (int s = 128; s > 0; s >>= 1) { if (tid < s) red[tid] += red[tid + s]; __syncthreads(); }
    float bs = red[0]; __syncthreads();
    red[tid] = lsq; __syncthreads();
    for (int s = 128; s > 0; s >>= 1) { if (tid < s) red[tid] += red[tid + s]; __syncthreads(); }
    if (tid == 0) {
        atomicAdd(dsum, (u64)to_fixed((double)bs));
        atomicAdd(dsq,  (u64)to_fixed((double)red[0]));
    }
}

__device__ __forceinline__ void stats_decode(const u64* stats, double cnt,
                                             float* mu, float* rs) {
    long long ss = (long long)stats[0], sq = (long long)stats[1];
    double mu_d = ((double)ss / STAT_SCALE) / cnt;
    double var  = ((double)sq / STAT_SCALE) / cnt - mu_d * mu_d;
    *mu = (float)mu_d;
    *rs = (float)(1.0 / sqrt(var + 1e-5));
}

#define PACK8(dstp, a, b) { \
    ushort_t o_[8] = {bf16_bits(a.x), bf16_bits(a.y), bf16_bits(a.z), bf16_bits(a.w), \
                      bf16_bits(b.x), bf16_bits(b.y), bf16_bits(b.z), bf16_bits(b.w)}; \
    *(uint4*)(dstp) = *(const uint4*)o_; }

// ---------------- K0: parallel init of cnt + stats ---------------------------
__global__ __launch_bounds__(256) void k0_init(int* __restrict__ cnt,
                                               u64* __restrict__ stats)
{
    int i = blockIdx.x * 256 + threadIdx.x;
    if (i < N_NODES) cnt[i] = 0;
    if (i < 4) stats[i] = 0ull;
}

// ---------------- K1: hpre = bf16(nf @ W1 + b1) + stats1 ---------------------
#define K1_TILES 1563
__global__ __launch_bounds__(256) void k1_gemm1(
    const float* __restrict__ nf, const float* __restrict__ W1,
    const float* __restrict__ b1, ushort_t* __restrict__ hpre,
    u64* __restrict__ stats, int nblocks)
{
    __shared__ bf16 Ash[2][64 * 136];
    __shared__ float red[256];
    const int tid = threadIdx.x;
    const int lane = tid & 63;
    const int w = tid >> 6;
    const int l15 = lane & 15, l4 = lane >> 4;

    bf16x8 bfrag[4][2];
    #pragma unroll
    for (int s = 0; s < 4; ++s)
        #pragma unroll
        for (int t = 0; t < 2; ++t) {
            int n = w * 32 + t * 16 + l15;
            #pragma unroll
            for (int j = 0; j < 8; ++j)
                bfrag[s][t][j] = (bf16)W1[(s * 32 + l4 * 8 + j) * DD + n];
        }
    float4 bias4[2];
    bias4[0] = *(const float4*)&b1[w * 32 + l4 * 4];
    bias4[1] = *(const float4*)&b1[w * 32 + 16 + l4 * 4];

    float lsum = 0.f, lsq = 0.f;
    const int srow = tid >> 2;
    const int q = tid & 3;

    float4 efr[8];
    {
        int grow = min(blockIdx.x * 64 + srow, N_NODES - 1);
        const float4* p = (const float4*)&nf[(size_t)grow * DD + q * 32];
        #pragma unroll
        for (int u = 0; u < 8; ++u) efr[u] = p[u];
    }

    int buf = 0;
    for (int tile = blockIdx.x; tile < K1_TILES; tile += nblocks) {
        const int rbase = tile * 64;
        #pragma unroll
        for (int u = 0; u < 4; ++u)
            PACK8(&Ash[buf][srow * 136 + q * 32 + u * 8], efr[2 * u], efr[2 * u + 1]);
        __syncthreads();
        int nt = tile + nblocks;
        if (nt < K1_TILES) {
            int grow = min(nt * 64 + srow, N_NODES - 1);
            const float4* p = (const float4*)&nf[(size_t)grow * DD + q * 32];
            #pragma unroll
            for (int u = 0; u < 8; ++u) efr[u] = p[u];
        }
        f32x4 acc[4][2];
        #pragma unroll
        for (int r = 0; r < 4; ++r)
            #pragma unroll
            for (int t = 0; t < 2; ++t)
                acc[r][t] = (f32x4){0.f, 0.f, 0.f, 0.f};
        #pragma unroll
        for (int s = 0; s < 4; ++s)
            #pragma unroll
            for (int r = 0; r < 4; ++r) {
                bf16x8 a = *(const bf16x8*)&Ash[buf][(r * 16 + l15) * 136 + s * 32 + l4 * 8];
                acc[r][0] = __builtin_amdgcn_mfma_f32_16x16x32_bf16(bfrag[s][0], a, acc[r][0], 0, 0, 0);
                acc[r][1] = __builtin_amdgcn_mfma_f32_16x16x32_bf16(bfrag[s][1], a, acc[r][1], 0, 0, 0);
            }
        #pragma unroll
        for (int r = 0; r < 4; ++r) {
            int row = rbase + r * 16 + l15;
            if (row < N_NODES) {
                #pragma unroll
                for (int t = 0; t < 2; ++t) {
                    int col = w * 32 + t * 16 + l4 * 4;
                    ushort_t o[4];
                    #pragma unroll
                    for (int j = 0; j < 4; ++j) {
                        float v = acc[r][t][j] + bias4[t][j];
                        lsum += v; lsq += v * v;
                        o[j] = bf16_bits(v);
                    }
                    *(uint2*)&hpre[(size_t)row * DD + col] = *(const uint2*)o;
                }
            }
        }
        buf ^= 1;
    }
    stats_atomic(lsum, lsq, red, &stats[0], &stats[1]);
}

// ---------------- K2b: hh = bf16( gelu(LN(hpre)) @ W2_bot + b2 ) -------------
__global__ __launch_bounds__(256) void k2b_gemmh(
    const ushort_t* __restrict__ hpre, const float* __restrict__ W2,
    const float* __restrict__ b2, const u64* __restrict__ stats,
    ushort_t* __restrict__ hh, int nblocks)
{
    __shared__ bf16 Ash[2][64 * 136];
    float mu, rs;
    stats_decode(stats, (double)N_NODES * DD, &mu, &rs);

    const int tid = threadIdx.x;
    const int lane = tid & 63;
    const int w = tid >> 6;
    const int l15 = lane & 15, l4 = lane >> 4;

    bf16x8 bfrag[4][2];
    #pragma unroll
    for (int s = 0; s < 4; ++s)
        #pragma unroll
        for (int t = 0; t < 2; ++t) {
            int n = w * 32 + t * 16 + l15;
            #pragma unroll
            for (int j = 0; j < 8; ++j)
                bfrag[s][t][j] = (bf16)W2[(DD + s * 32 + l4 * 8 + j) * DD + n];
        }
    float4 bias4[2];
    bias4[0] = *(const float4*)&b2[w * 32 + l4 * 4];
    bias4[1] = *(const float4*)&b2[w * 32 + 16 + l4 * 4];

    const int srow = tid >> 2;
    const int q = tid & 3;

    uint4 hr[4];
    {
        int grow = min(blockIdx.x * 64 + srow, N_NODES - 1);
        const uint4* p = (const uint4*)&hpre[(size_t)grow * DD + q * 32];
        #pragma unroll
        for (int u = 0; u < 4; ++u) hr[u] = p[u];
    }

    int buf = 0;
    for (int tile = blockIdx.x; tile < K1_TILES; tile += nblocks) {
        const int rbase = tile * 64;
        #pragma unroll
        for (int u = 0; u < 4; ++u) {
            const ushort_t* in = (const ushort_t*)&hr[u];
            ushort_t o[8];
            #pragma unroll
            for (int j = 0; j < 8; ++j)
                o[j] = bf16_bits(gelu_fast((bits_to_f(in[j]) - mu) * rs));
            *(uint4*)&Ash[buf][srow * 136 + q * 32 + u * 8] = *(const uint4*)o;
        }
        __syncthreads();
        int nt = tile + nblocks;
        if (nt < K1_TILES) {
            int grow = min(nt * 64 + srow, N_NODES - 1);
            const uint4* p = (const uint4*)&hpre[(size_t)grow * DD + q * 32];
            #pragma unroll
            for (int u = 0; u < 4; ++u) hr[u] = p[u];
        }
        f32x4 acc[4][2];
        #pragma unroll
        for (int r = 0; r < 4; ++r)
            #pragma unroll
            for (int t = 0; t < 2; ++t)
                acc[r][t] = (f32x4){0.f, 0.f, 0.f, 0.f};
        #pragma unroll
        for (int s = 0; s < 4; ++s)
            #pragma unroll
            for (int r = 0; r < 4; ++r) {
                bf16x8 a = *(const bf16x8*)&Ash[buf][(r * 16 + l15) * 136 + s * 32 + l4 * 8];
                acc[r][0] = __builtin_amdgcn_mfma_f32_16x16x32_bf16(bfrag[s][0], a, acc[r][0], 0, 0, 0);
                acc[r][1] = __builtin_amdgcn_mfma_f32_16x16x32_bf16(bfrag[s][1], a, acc[r][1], 0, 0, 0);
            }
        #pragma unroll
        for (int r = 0; r < 4; ++r) {
            int row = rbase + r * 16 + l15;
            if (row < N_NODES) {
                #pragma unroll
                for (int t = 0; t < 2; ++t) {
                    int col = w * 32 + t * 16 + l4 * 4;
                    ushort_t o[4];
                    #pragma unroll
                    for (int j = 0; j < 4; ++j)
                        o[j] = bf16_bits(acc[r][t][j] + bias4[t][j]);
                    *(uint2*)&hh[(size_t)row * DD + col] = *(const uint2*)o;
                }
            }
        }
        buf ^= 1;
    }
}

// ---------------- K4: e0 = bf16( ef @ W2_top + hh[src] ) + stats2 ------------
// Wave-owns-16-rows, B in LDS staged once, ZERO main-loop barriers,
// 2-phase register pipeline: src 2-ahead, panel+hv 1-ahead (A/B reg sets).
#define K4_WTILES (N_EDGES / 16)

#define K4_LOAD_SRC(dst, t) { if ((t) < K4_WTILES) dst = eidx[(size_t)((t) * 16 + l15) * 2]; }

#define K4_LOAD_PANEL(raw, t) { if ((t) < K4_WTILES) { \
    const float* base_ = &ef[(size_t)((t) * 16 + l15) * DD + l4 * 8]; \
    raw##0 = *(const float4*)(base_);       raw##1 = *(const float4*)(base_ + 4); \
    raw##2 = *(const float4*)(base_ + 32);  raw##3 = *(const float4*)(base_ + 36); \
    raw##4 = *(const float4*)(base_ + 64);  raw##5 = *(const float4*)(base_ + 68); \
    raw##6 = *(const float4*)(base_ + 96);  raw##7 = *(const float4*)(base_ + 100); } }

#define K4_LOAD_HV(hv, srcreg, t) { if ((t) < K4_WTILES) { \
    const ushort_t* hb_ = &hh[(size_t)(srcreg) * DD + l4 * 4]; \
    hv[0] = *(const uint2*)(hb_);       hv[1] = *(const uint2*)(hb_ + 16); \
    hv[2] = *(const uint2*)(hb_ + 32);  hv[3] = *(const uint2*)(hb_ + 48); \
    hv[4] = *(const uint2*)(hb_ + 64);  hv[5] = *(const uint2*)(hb_ + 80); \
    hv[6] = *(const uint2*)(hb_ + 96);  hv[7] = *(const uint2*)(hb_ + 112); } }

#define K4_COMPUTE_STORE(t, raw, hv) { \
    f32x4 acc[8]; \
    _Pragma("unroll") \
    for (int tt = 0; tt < 8; ++tt) acc[tt] = (f32x4){0.f, 0.f, 0.f, 0.f}; \
    _Pragma("unroll") \
    for (int s = 0; s < 4; ++s) { \
        float4 ra_ = raw##_arr(2 * s), rb_ = raw##_arr(2 * s + 1); \
        ushort_t af_[8] = {bf16_bits(ra_.x), bf16_bits(ra_.y), bf16_bits(ra_.z), bf16_bits(ra_.w), \
                           bf16_bits(rb_.x), bf16_bits(rb_.y), bf16_bits(rb_.z), bf16_bits(rb_.w)}; \
        bf16x8 afrag = *(const bf16x8*)af_; \
        _Pragma("unroll") \
        for (int tt = 0; tt < 8; ++tt) { \
            bf16x8 bfr = *(const bf16x8*)&Bsh[(tt * 16 + l15) * 136 + s * 32 + l4 * 8]; \
            acc[tt] = __builtin_amdgcn_mfma_f32_16x16x32_bf16(bfr, afrag, acc[tt], 0, 0, 0); \
        } \
    } \
    const int row_ = (t) * 16 + l15; \
    _Pragma("unroll") \
    for (int tt = 0; tt < 8; ++tt) { \
        float hadd_[4] = {bits_to_f((ushort_t)(hv[tt].x & 0xffff)), \
                          bits_to_f((ushort_t)(hv[tt].x >> 16)), \
                          bits_to_f((ushort_t)(hv[tt].y & 0xffff)), \
                          bits_to_f((ushort_t)(hv[tt].y >> 16))}; \
        ushort_t o_[4]; \
        _Pragma("unroll") \
        for (int j = 0; j < 4; ++j) { \
            float v_ = acc[tt][j] + hadd_[j]; \
            lsum += v_; lsq += v_ * v_; \
            o_[j] = bf16_bits(v_); \
        } \
        *(uint2*)&e0[(size_t)row_ * DD + tt * 16 + l4 * 4] = *(const uint2*)o_; \
    } }

__global__ __launch_bounds__(256) void k4_gemm2(
    const float* __restrict__ ef, const ushort_t* __restrict__ hh,
    const int* __restrict__ eidx, const float* __restrict__ W2,
    ushort_t* __restrict__ e0, u64* __restrict__ stats, int nblocks)
{
    __shared__ bf16 Bsh[128 * 136];
    __shared__ float red[256];
    const int tid = threadIdx.x;
    const int lane = tid & 63;
    const int w = tid >> 6;
    const int l15 = lane & 15, l4 = lane >> 4;

    // stage W2_top transposed: Bsh[n*136 + k] = bf16(W2[k*128 + n]); 256 threads
    {
        int n = tid & 127;
        int kb0 = (tid >> 7) * 8;
        #pragma unroll
        for (int i = 0; i < 8; ++i) {
            int kb = kb0 + i;
            ushort_t o[8];
            #pragma unroll
            for (int j = 0; j < 8; ++j)
                o[j] = bf16_bits(W2[(size_t)(kb * 8 + j) * DD + n]);
            *(uint4*)&Bsh[n * 136 + kb * 8] = *(const uint4*)o;
        }
    }
    __syncthreads();

    float lsum = 0.f, lsq = 0.f;
    const int S = nblocks * 4;

    float4 rA0, rA1, rA2, rA3, rA4, rA5, rA6, rA7;
    float4 rB0, rB1, rB2, rB3, rB4, rB5, rB6, rB7;
    #define rA_arr(i) (i==0?rA0:i==1?rA1:i==2?rA2:i==3?rA3:i==4?rA4:i==5?rA5:i==6?rA6:rA7)
    #define rB_arr(i) (i==0?rB0:i==1?rB1:i==2?rB2:i==3?rB3:i==4?rB4:i==5?rB5:i==6?rB6:rB7)
    uint2 hvA[8], hvB[8];
    int srcA = 0, srcB = 0, srcC = 0;

    int g = blockIdx.x * 4 + w;
    // prologue: panel(g), src(g)->hv(g), src(g+S)
    K4_LOAD_SRC(srcA, g);
    K4_LOAD_PANEL(rA, g);
    K4_LOAD_SRC(srcB, g + S);
    K4_LOAD_HV(hvA, srcA, g);

    while (g < K4_WTILES) {
        // phase A: current = (rA, hvA) at tile g; srcB = src(g+S) resident
        {
            K4_LOAD_SRC(srcC, g + 2 * S);
            K4_LOAD_HV(hvB, srcB, g + S);
            K4_LOAD_PANEL(rB, g + S);
            K4_COMPUTE_STORE(g, rA, hvA);
        }
        g += S;
        if (g >= K4_WTILES) break;
        // phase B: current = (rB, hvB) at tile g; srcC = src(g+S) resident
        {
            K4_LOAD_SRC(srcB, g + 2 * S);
            K4_LOAD_HV(hvA, srcC, g + S);
            K4_LOAD_PANEL(rA, g + S);
            K4_COMPUTE_STORE(g, rB, hvB);
        }
        g += S;
    }
    stats_atomic(lsum, lsq, red, &stats[2], &stats[3]);
}

// ---------------- K7: bucket edges by dst ------------------------------------
__global__ __launch_bounds__(256) void k7_fill(
    const int* __restrict__ eidx, int* __restrict__ cnt, int* __restrict__ slot)
{
    int e = blockIdx.x * 256 + threadIdx.x;
    if (e >= N_EDGES) return;
    int dst = eidx[(size_t)e * 2 + 1];
    int pos = atomicAdd(&cnt[dst], 1);
    if (pos < MAXDEG) slot[dst * MAXDEG + pos] = e;
}

// ---------------- K8: per-node gather + norm + fast-gelu + mean --------------
__global__ __launch_bounds__(256) void k8_gather(
    const ushort_t* __restrict__ e0v, const int* __restrict__ slot,
    const int* __restrict__ cnt, const u64* __restrict__ stats,
    float* __restrict__ out)
{
    float mu, rs;
    stats_decode(stats + 2, (double)N_EDGES * DD, &mu, &rs);
    int node = (int)((blockIdx.x * 256 + threadIdx.x) >> 6);
    int lane = threadIdx.x & 63;
    if (node >= N_NODES) return;
    const int hl = lane >> 5;
    const int l31 = lane & 31;
    int c = cnt[node];
    int m = min(c, MAXDEG);
    int myslot = (lane < m) ? slot[node * MAXDEG + lane] : 0;
    float a0 = 0.f, a1 = 0.f, a2 = 0.f, a3 = 0.f;
    const size_t off = (size_t)(l31 * 4);

    int steps = m >> 1;
    int s = 0;
    for (; s + 2 <= steps; s += 2) {
        int eA = __shfl(myslot, 2 * s + hl);
        int eB = __shfl(myslot, 2 * (s + 1) + hl);
        uint2 uA = *(const uint2*)&e0v[(size_t)eA * DD + off];
        uint2 uB = *(const uint2*)&e0v[(size_t)eB * DD + off];
        a0 += gelu_fast((__uint_as_float(uA.x << 16) - mu) * rs);
        a1 += gelu_fast((__uint_as_float(uA.x & 0xffff0000u) - mu) * rs);
        a2 += gelu_fast((__uint_as_float(uA.y << 16) - mu) * rs);
        a3 += gelu_fast((__uint_as_float(uA.y & 0xffff0000u) - mu) * rs);
        a0 += gelu_fast((__uint_as_float(uB.x << 16) - mu) * rs);
        a1 += gelu_fast((__uint_as_float(uB.x & 0xffff0000u) - mu) * rs);
        a2 += gelu_fast((__uint_as_float(uB.y << 16) - mu) * rs);
        a3 += gelu_fast((__uint_as_float(uB.y & 0xffff0000u) - mu) * rs);
    }
    for (; s < steps; ++s) {
        int eA = __shfl(myslot, 2 * s + hl);
        uint2 uA = *(const uint2*)&e0v[(size_t)eA * DD + off];
        a0 += gelu_fast((__uint_as_float(uA.x << 16) - mu) * rs);
        a1 += gelu_fast((__uint_as_float(uA.x & 0xffff0000u) - mu) * rs);
        a2 += gelu_fast((__uint_as_float(uA.y << 16) - mu) * rs);
        a3 += gelu_fast((__uint_as_float(uA.y & 0xffff0000u) - mu) * rs);
    }
    if (m & 1) {
        int eA = __shfl(myslot, m - 1);
        uint2 uA = *(const uint2*)&e0v[(size_t)eA * DD + off];
        float g0 = gelu_fast((__uint_as_float(uA.x << 16) - mu) * rs);
        float g1 = gelu_fast((__uint_as_float(uA.x & 0xffff0000u) - mu) * rs);
        float g2 = gelu_fast((__uint_as_float(uA.y << 16) - mu) * rs);
        float g3 = gelu_fast((__uint_as_float(uA.y & 0xffff0000u) - mu) * rs);
        if (hl == 0) { a0 += g0; a1 += g1; a2 += g2; a3 += g3; }
    }
    a0 += __shfl_xor(a0, 32);
    a1 += __shfl_xor(a1, 32);
    a2 += __shfl_xor(a2, 32);
    a3 += __shfl_xor(a3, 32);
    if (hl == 0) {
        float inv = c > 0 ? 1.0f / (float)c : 0.f;
        float4 res = {a0 * inv, a1 * inv, a2 * inv, a3 * inv};
        *(float4*)&out[(size_t)node * DD + l31 * 4] = res;
    }
}

// ---------------- launch -----------------------------------------------------
extern "C" void kernel_launch(void* const* d_in, const int* in_sizes, int n_in,
                              void* d_out, int out_size, void* d_ws, size_t ws_size,
                              hipStream_t stream) {
    const float* ef  = (const float*)d_in[0];
    const float* nf  = (const float*)d_in[1];
    const int*   eix = (const int*)d_in[2];
    const float* W1  = (const float*)d_in[3];
    const float* b1  = (const float*)d_in[4];
    const float* W2  = (const float*)d_in[5];
    const float* b2  = (const float*)d_in[6];
    float* out = (float*)d_out;
    char* ws = (char*)d_ws;

    ushort_t* hpre  = (ushort_t*)(ws + 0);           // 25,600,000
    ushort_t* hh    = (ushort_t*)(ws + 25600000);    // 25,600,000
    ushort_t* e0    = (ushort_t*)(ws + 51200000);    // 163,840,000
    int*      cnt   = (int*)(ws + 215040000);        // 400,000
    u64*      stats = (u64*)(ws + 215440000);        // 64 B
    int*      slot  = (int*)(ws + 215440064);        // 25,600,000

    k0_init<<<391, 256, 0, stream>>>(cnt, stats);
    k7_fill<<<2500, 256, 0, stream>>>(eix, cnt, slot);
    k1_gemm1<<<782, 256, 0, stream>>>(nf, W1, b1, hpre, stats, 782);
    k2b_gemmh<<<782, 256, 0, stream>>>(hpre, W2, b2, stats, hh, 782);
    k4_gemm2<<<1024, 256, 0, stream>>>(ef, hh, eix, W2, e0, stats, 1024);
    k8_gather<<<25000, 256, 0, stream>>>(e0, slot, cnt, stats, out);
}